// Round 5
// baseline (388.790 us; speedup 1.0000x reference)
//
#include <hip/hip_runtime.h>
#include <hip/hip_bf16.h>

// ---------- problem constants ----------
constexpr int Nrows = 8192;   // batch rows
constexpr int L     = 256;    // input_len / features
constexpr int D     = 128;    // hidden per head
constexpr float EPS = 1e-5f;

typedef __bf16 bf16x8 __attribute__((ext_vector_type(8)));
typedef __bf16 bf16x4 __attribute__((ext_vector_type(4)));
typedef float  f32x4  __attribute__((ext_vector_type(4)));

#define MFMA16(a, b, c) __builtin_amdgcn_mfma_f32_16x16x32_bf16((a), (b), (c), 0, 0, 0)

// ============================================================
// param convert+transpose (fp32 -> bf16) + stats zeroing
// ============================================================
__global__ void k_cvt_params(const float* __restrict__ Q, const float* __restrict__ K,
                             const float* __restrict__ Vd, const float* __restrict__ Vup,
                             const float* __restrict__ W,
                             __bf16* __restrict__ Bt, __bf16* __restrict__ VupT,
                             __bf16* __restrict__ Wb, float* __restrict__ stats) {
    if (blockIdx.x == 0) {
        f32x4 zz = {0.f, 0.f, 0.f, 0.f};
        ((f32x4*)stats)[threadIdx.x] = zz;
    }
    int i = blockIdx.x * 256 + threadIdx.x;
    if (i < 6 * 128 * 256) {
        int g = i >> 15; int r = i & 32767; int d = r >> 8; int l = r & 255;
        const float* src = (g % 3 == 0 ? Q : (g % 3 == 1 ? K : Vd)) + (g / 3) * (L * D);
        Bt[i] = (__bf16)src[l * D + d];
    } else if (i < 8 * 128 * 256) {
        int j = i - 6 * 128 * 256;
        int h = j >> 15; int r = j & 32767; int l = r >> 7; int d = r & 127;
        VupT[j] = (__bf16)Vup[h * (D * L) + d * L + l];
    } else {
        int j = i - 8 * 128 * 256;
        Wb[j] = (__bf16)W[j];
    }
}

// ============================================================
// batchnorm stats: per-column sum / sumsq over 8192 rows (fp32 input)
// ============================================================
__global__ void k_bn_stats(const float* __restrict__ x, float* __restrict__ sum,
                           float* __restrict__ sq) {
    int col = threadIdx.x;
    int r0 = blockIdx.x * 32;          // 256 blocks x 32 rows
    float s = 0.f, s2 = 0.f;
    for (int i = 0; i < 32; i++) {
        float v = x[(r0 + i) * L + col];
        s += v; s2 += v * v;
    }
    atomicAdd(&sum[col], s);
    atomicAdd(&sq[col], s2);
}

// ============================================================
// batchnorm normalize: bn1 emits bf16 (GEMM operand) + fp32 (residual)
// ============================================================
__global__ void k_bn_norm1(const float* __restrict__ x, const float* __restrict__ sum,
                           const float* __restrict__ sq, __bf16* __restrict__ hb,
                           float* __restrict__ hf) {
    int i = (blockIdx.x * 256 + threadIdx.x) * 4;
    int col = i & (L - 1);
    f32x4 v = *(const f32x4*)(x + i);
    bf16x4 o; f32x4 of;
#pragma unroll
    for (int j = 0; j < 4; j++) {
        float m   = sum[col + j] * (1.0f / Nrows);
        float var = sq[col + j] * (1.0f / Nrows) - m * m;
        float rs  = rsqrtf(var + EPS);
        float t = (v[j] - m) * rs;
        of[j] = t; o[j] = (__bf16)t;
    }
    *(bf16x4*)(hb + i) = o;
    *(f32x4*)(hf + i) = of;
}

__global__ void k_bn_norm2(const float* __restrict__ z, const float* __restrict__ sum,
                           const float* __restrict__ sq, __bf16* __restrict__ h) {
    int i = (blockIdx.x * 256 + threadIdx.x) * 4;
    int col = i & (L - 1);
    f32x4 v = *(const f32x4*)(z + i);
    bf16x4 o;
#pragma unroll
    for (int j = 0; j < 4; j++) {
        float m   = sum[col + j] * (1.0f / Nrows);
        float var = sq[col + j] * (1.0f / Nrows) - m * m;
        float rs  = rsqrtf(var + EPS);
        o[j] = (__bf16)((v[j] - m) * rs);
    }
    *(bf16x4*)(h + i) = o;
}

// ============================================================
// QKV projection: 64-row M-tiles (grid 128x6=768 blocks), wave=16 rows.
// q/k row-major [8192][128]; v TRANSPOSED Vt[head][128][8192]
// ============================================================
__launch_bounds__(256)
__global__ void k_gemm_qkv(const __bf16* __restrict__ h, const __bf16* __restrict__ Bt,
                           __bf16* __restrict__ q0, __bf16* __restrict__ k0,
                           __bf16* __restrict__ q1, __bf16* __restrict__ k1,
                           __bf16* __restrict__ Vt) {
    int g = blockIdx.y;
    int m0 = blockIdx.x * 64;
    int w = threadIdx.x >> 6, lane = threadIdx.x & 63;
    int c = lane & 15, qd = lane >> 4;
    int mw = m0 + w * 16;
    const __bf16* B = Bt + g * (128 * 256);

    f32x4 acc[8] = {};
#pragma unroll
    for (int kc = 0; kc < 8; kc++) {
        bf16x8 a = *(const bf16x8*)(h + (mw + c) * L + kc * 32 + qd * 8);
#pragma unroll
        for (int nt = 0; nt < 8; nt++) {
            bf16x8 b = *(const bf16x8*)(B + (nt * 16 + c) * L + kc * 32 + qd * 8);
            acc[nt] = MFMA16(a, b, acc[nt]);
        }
    }
    if (g == 2 || g == 5) {
        __bf16* vt = Vt + (g / 3) * (128 * Nrows);
#pragma unroll
        for (int nt = 0; nt < 8; nt++)
#pragma unroll
            for (int r = 0; r < 4; r++)
                vt[(nt * 16 + c) * Nrows + mw + 4 * qd + r] = (__bf16)acc[nt][r];
    } else {
        __bf16* dst = (g == 0) ? q0 : (g == 1) ? k0 : (g == 3) ? q1 : k1;
#pragma unroll
        for (int nt = 0; nt < 8; nt++)
#pragma unroll
            for (int r = 0; r < 4; r++)
                dst[(mw + 4 * qd + r) * D + nt * 16 + c] = (__bf16)acc[nt][r];
    }
}

// ============================================================
// Flash attention (no-max online softmax: logits bounded |s|<~13).
// Grid = 256 blocks (qtile*2+head) -> 1 block/CU, head==XCD parity so each
// XCD's L2 holds one head's K+Vt (4MB): measured ~18MB FETCH at round 2.
// Block = 512 threads (8 waves) = 2 row-groups x 4 key-slices:
// each wave owns 32 Q-rows x 64-wide key slice of a 256-key outer step.
// Per-wave regs ~195 (64 AGPR acc + ~130 VGPR) <= 256 -> TRUE 2 waves/SIMD,
// no spills (round-4 config demanded 292 -> spilled at the 256 cap).
// Main loop is barrier-free (P round-trip is wave-private LDS).
// ============================================================
__launch_bounds__(512, 2)
__global__ void k_flash(const __bf16* __restrict__ q0, const __bf16* __restrict__ k0,
                        const __bf16* __restrict__ q1, const __bf16* __restrict__ k1,
                        const __bf16* __restrict__ Vt, __bf16* __restrict__ O) {
    int head = blockIdx.x & 1;
    int qtile = blockIdx.x >> 1;       // 0..127
    int m0 = qtile * 64;
    const __bf16* qm = head ? q1 : q0;
    const __bf16* km = head ? k1 : k0;
    const __bf16* vt = Vt + head * (128 * Nrows);
    __bf16* Og = O + head * (Nrows * D);

    int tid = threadIdx.x;
    int w = tid >> 6, lane = tid & 63;
    int g = w >> 2, ks = w & 3;        // row-group, key-slice
    int c = lane & 15, qd = lane >> 4;

    // LDS: Pb[8][32*72] bf16 (36864 B) aliased with obuf[8][32][16] f32 (16384 B);
    // l_red[8][32] + l_inv[64] in the tail. Total 38144 B.
    __shared__ char smem[8 * 32 * 72 * 2 + 8 * 32 * 4 + 64 * 4];
    __bf16* Pb = (__bf16*)smem;
    float (*obuf)[32][16] = (float (*)[32][16])smem;
    float (*l_red)[32] = (float (*)[32])(smem + 8 * 32 * 72 * 2);
    float* l_inv = (float*)(smem + 8 * 32 * 72 * 2 + 8 * 32 * 4);

    int mrow = m0 + g * 32;
    bf16x8 aq[2][4];
#pragma unroll
    for (int mt = 0; mt < 2; mt++)
#pragma unroll
        for (int kc = 0; kc < 4; kc++)
            aq[mt][kc] = *(const bf16x8*)(qm + (mrow + mt * 16 + c) * D + kc * 32 + qd * 8);

    f32x4 oacc[2][8] = {};
    float lp[2][4] = {};
    __bf16* Pw = Pb + w * (32 * 72);

    for (int n0 = 0; n0 < Nrows; n0 += 256) {
        int nb = n0 + ks * 64;           // this wave's 64-wide key slice
        // S = Q K^T over 4 n-tiles; P = exp(S) into wave-private LDS
#pragma unroll
        for (int nt = 0; nt < 4; nt++) {
            bf16x8 kb[4];
#pragma unroll
            for (int kc = 0; kc < 4; kc++)
                kb[kc] = *(const bf16x8*)(km + (nb + nt * 16 + c) * D + kc * 32 + qd * 8);
            f32x4 s[2] = {};
#pragma unroll
            for (int kc = 0; kc < 4; kc++) {
                s[0] = MFMA16(aq[0][kc], kb[kc], s[0]);
                s[1] = MFMA16(aq[1][kc], kb[kc], s[1]);
            }
#pragma unroll
            for (int mt = 0; mt < 2; mt++)
#pragma unroll
                for (int r = 0; r < 4; r++) {
                    float e = __expf(s[mt][r]);
                    lp[mt][r] += e;
                    Pw[(mt * 16 + 4 * qd + r) * 72 + nt * 16 + c] = (__bf16)e;
                }
        }
        // P·V: A-frags from LDS (A layout), B-frags from Vt rows
        bf16x8 ap[2][2];
#pragma unroll
        for (int mt = 0; mt < 2; mt++)
#pragma unroll
            for (int kk = 0; kk < 2; kk++)
                ap[mt][kk] = *(const bf16x8*)(Pw + (mt * 16 + c) * 72 + kk * 32 + qd * 8);
#pragma unroll
        for (int dvt = 0; dvt < 8; dvt++) {
            bf16x8 v0 = *(const bf16x8*)(vt + (dvt * 16 + c) * Nrows + nb + qd * 8);
            bf16x8 v1 = *(const bf16x8*)(vt + (dvt * 16 + c) * Nrows + nb + 32 + qd * 8);
#pragma unroll
            for (int mt = 0; mt < 2; mt++) {
                oacc[mt][dvt] = MFMA16(ap[mt][0], v0, oacc[mt][dvt]);
                oacc[mt][dvt] = MFMA16(ap[mt][1], v1, oacc[mt][dvt]);
            }
        }
    }

    // per-wave row sums of l (sum over the 16 column-lanes)
#pragma unroll
    for (int mt = 0; mt < 2; mt++)
#pragma unroll
        for (int r = 0; r < 4; r++) {
            float v = lp[mt][r];
            v += __shfl_xor(v, 1, 16);
            v += __shfl_xor(v, 2, 16);
            v += __shfl_xor(v, 4, 16);
            v += __shfl_xor(v, 8, 16);
            lp[mt][r] = v;
        }
    if (c == 0) {
#pragma unroll
        for (int mt = 0; mt < 2; mt++)
#pragma unroll
            for (int r = 0; r < 4; r++)
                l_red[w][mt * 16 + 4 * qd + r] = lp[mt][r];
    }
    __syncthreads();   // main loop + l_red done everywhere -> Pb->obuf alias safe
    if (tid < 64) {
        int gg = tid >> 5, rl = tid & 31;
        float lt = l_red[gg * 4 + 0][rl] + l_red[gg * 4 + 1][rl] +
                   l_red[gg * 4 + 2][rl] + l_red[gg * 4 + 3][rl];
        l_inv[tid] = 1.0f / lt;
    }

    // combine the 4 key-slice partials per row-group, one dv-tile at a time
    for (int dvt = 0; dvt < 8; dvt++) {
        __syncthreads();      // l_inv ready (iter 0); prior readers done (later iters)
#pragma unroll
        for (int mt = 0; mt < 2; mt++)
#pragma unroll
            for (int r = 0; r < 4; r++)
                obuf[w][mt * 16 + 4 * qd + r][c] = oacc[mt][dvt][r];
        __syncthreads();
        if (tid < 256) {
            int row = tid >> 2, col = (tid & 3) * 4;   // row 0..63, col 0,4,8,12
            int gg = row >> 5, rl = row & 31;
            f32x4 s = {0.f, 0.f, 0.f, 0.f};
#pragma unroll
            for (int k2 = 0; k2 < 4; k2++) s += *(const f32x4*)&obuf[gg * 4 + k2][rl][col];
            float il = l_inv[row];
            bf16x4 o;
#pragma unroll
            for (int e = 0; e < 4; e++) o[e] = (__bf16)(s[e] * il);
            *(bf16x4*)(Og + (m0 + row) * D + dvt * 16 + col) = o;
        }
    }
}

// ============================================================
// z = hf + O0 @ Vup0 + O1 @ Vup1   (fp32 residual + fp32 out)
// 64-row tiles: grid (128, 2) = 256 blocks
// ============================================================
__launch_bounds__(256)
__global__ void k_gemm_vup(const __bf16* __restrict__ O, const __bf16* __restrict__ VupT,
                           const float* __restrict__ hf, float* __restrict__ z) {
    int n0 = blockIdx.y * 128;
    int m0 = blockIdx.x * 64;
    int w = threadIdx.x >> 6, lane = threadIdx.x & 63;
    int c = lane & 15, qd = lane >> 4;
    int mw = m0 + w * 16;

    f32x4 acc[8] = {};
#pragma unroll
    for (int kc = 0; kc < 8; kc++) {
        const __bf16* Oh = O + (kc >> 2) * (Nrows * D);
        const __bf16* Vh = VupT + (kc >> 2) * (L * D);
        int ko = (kc & 3) * 32 + qd * 8;
        bf16x8 a = *(const bf16x8*)(Oh + (mw + c) * D + ko);
#pragma unroll
        for (int nt = 0; nt < 8; nt++) {
            bf16x8 b = *(const bf16x8*)(Vh + (n0 + nt * 16 + c) * D + ko);
            acc[nt] = MFMA16(a, b, acc[nt]);
        }
    }
#pragma unroll
    for (int nt = 0; nt < 8; nt++)
#pragma unroll
        for (int r = 0; r < 4; r++) {
            int row = mw + 4 * qd + r;
            int col = n0 + nt * 16 + c;
            z[row * L + col] = acc[nt][r] + hf[row * L + col];
        }
}

// ============================================================
// out = relu(hin @ W^T + b); 64-row tiles: grid (128, 2) = 256 blocks
// ============================================================
template <typename OutT>
__launch_bounds__(256)
__global__ void k_gemm_w(const __bf16* __restrict__ hin, const __bf16* __restrict__ W,
                         const float* __restrict__ bias, OutT* __restrict__ out) {
    int n0 = blockIdx.y * 128;
    int m0 = blockIdx.x * 64;
    int w = threadIdx.x >> 6, lane = threadIdx.x & 63;
    int c = lane & 15, qd = lane >> 4;
    int mw = m0 + w * 16;

    f32x4 acc[8] = {};
#pragma unroll
    for (int kc = 0; kc < 8; kc++) {
        bf16x8 a = *(const bf16x8*)(hin + (mw + c) * L + kc * 32 + qd * 8);
#pragma unroll
        for (int nt = 0; nt < 8; nt++) {
            bf16x8 b = *(const bf16x8*)(W + (n0 + nt * 16 + c) * L + kc * 32 + qd * 8);
            acc[nt] = MFMA16(a, b, acc[nt]);
        }
    }
#pragma unroll
    for (int nt = 0; nt < 8; nt++) {
        int col = n0 + nt * 16 + c;
        float bv = bias[col];
#pragma unroll
        for (int r = 0; r < 4; r++) {
            int row = mw + 4 * qd + r;
            float v = fmaxf(acc[nt][r] + bv, 0.0f);
            out[row * L + col] = (OutT)v;
        }
    }
}

// ============================================================
extern "C" void kernel_launch(void* const* d_in, const int* in_sizes, int n_in,
                              void* d_out, int out_size, void* d_ws, size_t ws_size,
                              hipStream_t stream) {
    (void)in_sizes; (void)n_in; (void)out_size; (void)ws_size;
    const float* x   = (const float*)d_in[0];
    const float* Q   = (const float*)d_in[1];
    const float* K   = (const float*)d_in[2];
    const float* Vd  = (const float*)d_in[3];
    const float* Vup = (const float*)d_in[4];
    const float* W   = (const float*)d_in[5];
    const float* b   = (const float*)d_in[6];
    float* out = (float*)d_out;

    char* ws = (char*)d_ws;
    size_t off = 0;
    auto alloc = [&](size_t bytes) -> void* {
        void* p = ws + off;
        off += (bytes + 255) & ~(size_t)255;
        return p;
    };
    float*  stats = (float*)alloc(4 * 256 * sizeof(float)); // sum1,sq1,sum2,sq2
    __bf16* Bt    = (__bf16*)alloc(6 * 128 * 256 * 2);
    __bf16* VupT  = (__bf16*)alloc(2 * 256 * 128 * 2);
    __bf16* Wb    = (__bf16*)alloc(2 * 256 * 256 * 2);
    __bf16* hb    = (__bf16*)alloc((size_t)Nrows * L * 2);
    float*  hf    = (float*)alloc((size_t)Nrows * L * 4);
    __bf16* q0    = (__bf16*)alloc((size_t)Nrows * D * 2);
    __bf16* k0    = (__bf16*)alloc((size_t)Nrows * D * 2);
    __bf16* q1    = (__bf16*)alloc((size_t)Nrows * D * 2);
    __bf16* k1    = (__bf16*)alloc((size_t)Nrows * D * 2);
    __bf16* Vt    = (__bf16*)alloc((size_t)2 * 128 * Nrows * 2);
    __bf16* O     = (__bf16*)alloc((size_t)2 * Nrows * D * 2);
    float*  z     = (float*)alloc((size_t)Nrows * L * 4);
    __bf16* h2    = (__bf16*)alloc((size_t)Nrows * L * 2);
    __bf16* h3    = (__bf16*)alloc((size_t)Nrows * L * 2);

    float* sum1 = stats, *sq1 = stats + 256, *sum2 = stats + 512, *sq2 = stats + 768;

    k_cvt_params<<<1536, 256, 0, stream>>>(Q, K, Vd, Vup, W, Bt, VupT, Wb, stats);
    k_bn_stats<<<256, 256, 0, stream>>>(x, sum1, sq1);
    k_bn_norm1<<<2048, 256, 0, stream>>>(x, sum1, sq1, hb, hf);
    k_gemm_qkv<<<dim3(128, 6), 256, 0, stream>>>(hb, Bt, q0, k0, q1, k1, Vt);
    k_flash<<<256, 512, 0, stream>>>(q0, k0, q1, k1, Vt, O);
    k_gemm_vup<<<dim3(128, 2), 256, 0, stream>>>(O, VupT, hf, z);
    k_bn_stats<<<256, 256, 0, stream>>>(z, sum2, sq2);
    k_bn_norm2<<<2048, 256, 0, stream>>>(z, sum2, sq2, h2);
    k_gemm_w<__bf16><<<dim3(128, 2), 256, 0, stream>>>(h2, Wb, b, h3);
    k_gemm_w<float><<<dim3(128, 2), 256, 0, stream>>>(h3, Wb + 256 * 256, b + 256, out);
}

// Round 6
// 387.842 us; speedup vs baseline: 1.0024x; 1.0024x over previous
//
#include <hip/hip_runtime.h>
#include <hip/hip_bf16.h>

// ---------- problem constants ----------
constexpr int Nrows = 8192;   // batch rows
constexpr int L     = 256;    // input_len / features
constexpr int D     = 128;    // hidden per head
constexpr float EPS = 1e-5f;

typedef __bf16 bf16x8 __attribute__((ext_vector_type(8)));
typedef __bf16 bf16x4 __attribute__((ext_vector_type(4)));
typedef float  f32x4  __attribute__((ext_vector_type(4)));

#define MFMA16(a, b, c) __builtin_amdgcn_mfma_f32_16x16x32_bf16((a), (b), (c), 0, 0, 0)

// ============================================================
// fused pre-pass: param convert+transpose (blocks 0..1535) and
// bn1 column stats for x (blocks 1536..1791). stats pre-zeroed by memset.
// ============================================================
__global__ void k_pre(const float* __restrict__ x,
                      const float* __restrict__ Q, const float* __restrict__ K,
                      const float* __restrict__ Vd, const float* __restrict__ Vup,
                      const float* __restrict__ W,
                      __bf16* __restrict__ Bt, __bf16* __restrict__ VupT,
                      __bf16* __restrict__ Wb, float* __restrict__ sum,
                      float* __restrict__ sq) {
    if (blockIdx.x >= 1536) {            // bn stats: 256 blocks x 32 rows
        int col = threadIdx.x;
        int r0 = (blockIdx.x - 1536) * 32;
        float s = 0.f, s2 = 0.f;
        for (int i = 0; i < 32; i++) {
            float v = x[(r0 + i) * L + col];
            s += v; s2 += v * v;
        }
        atomicAdd(&sum[col], s);
        atomicAdd(&sq[col], s2);
        return;
    }
    int i = blockIdx.x * 256 + threadIdx.x;
    if (i < 6 * 128 * 256) {
        int g = i >> 15; int r = i & 32767; int d = r >> 8; int l = r & 255;
        const float* src = (g % 3 == 0 ? Q : (g % 3 == 1 ? K : Vd)) + (g / 3) * (L * D);
        Bt[i] = (__bf16)src[l * D + d];
    } else if (i < 8 * 128 * 256) {
        int j = i - 6 * 128 * 256;
        int h = j >> 15; int r = j & 32767; int l = r >> 7; int d = r & 127;
        VupT[j] = (__bf16)Vup[h * (D * L) + d * L + l];
    } else {
        int j = i - 8 * 128 * 256;
        Wb[j] = (__bf16)W[j];
    }
}

// ============================================================
// batchnorm stats for z (fp32)
// ============================================================
__global__ void k_bn_stats(const float* __restrict__ x, float* __restrict__ sum,
                           float* __restrict__ sq) {
    int col = threadIdx.x;
    int r0 = blockIdx.x * 32;          // 256 blocks x 32 rows
    float s = 0.f, s2 = 0.f;
    for (int i = 0; i < 32; i++) {
        float v = x[(r0 + i) * L + col];
        s += v; s2 += v * v;
    }
    atomicAdd(&sum[col], s);
    atomicAdd(&sq[col], s2);
}

// ============================================================
// batchnorm normalize: bn1 emits bf16 (GEMM operand) + fp32 (residual)
// ============================================================
__global__ void k_bn_norm1(const float* __restrict__ x, const float* __restrict__ sum,
                           const float* __restrict__ sq, __bf16* __restrict__ hb,
                           float* __restrict__ hf) {
    int i = (blockIdx.x * 256 + threadIdx.x) * 4;
    int col = i & (L - 1);
    f32x4 v = *(const f32x4*)(x + i);
    bf16x4 o; f32x4 of;
#pragma unroll
    for (int j = 0; j < 4; j++) {
        float m   = sum[col + j] * (1.0f / Nrows);
        float var = sq[col + j] * (1.0f / Nrows) - m * m;
        float rs  = rsqrtf(var + EPS);
        float t = (v[j] - m) * rs;
        of[j] = t; o[j] = (__bf16)t;
    }
    *(bf16x4*)(hb + i) = o;
    *(f32x4*)(hf + i) = of;
}

__global__ void k_bn_norm2(const float* __restrict__ z, const float* __restrict__ sum,
                           const float* __restrict__ sq, __bf16* __restrict__ h) {
    int i = (blockIdx.x * 256 + threadIdx.x) * 4;
    int col = i & (L - 1);
    f32x4 v = *(const f32x4*)(z + i);
    bf16x4 o;
#pragma unroll
    for (int j = 0; j < 4; j++) {
        float m   = sum[col + j] * (1.0f / Nrows);
        float var = sq[col + j] * (1.0f / Nrows) - m * m;
        float rs  = rsqrtf(var + EPS);
        o[j] = (__bf16)((v[j] - m) * rs);
    }
    *(bf16x4*)(h + i) = o;
}

// ============================================================
// QKV projection: 64-row M-tiles (grid 128x6), wave = 16 rows.
// q/k row-major [8192][128]. v: repacked through LDS and stored
// TRANSPOSED Vt[head][128][8192] with 16B/lane stores (the old direct
// C-layout store was 64 x 2B scatter to rows 16KB apart per inst).
// ============================================================
__launch_bounds__(256)
__global__ void k_gemm_qkv(const __bf16* __restrict__ h, const __bf16* __restrict__ Bt,
                           __bf16* __restrict__ q0, __bf16* __restrict__ k0,
                           __bf16* __restrict__ q1, __bf16* __restrict__ k1,
                           __bf16* __restrict__ Vt) {
    __shared__ __bf16 lv[64][130];
    int g = blockIdx.y;
    int m0 = blockIdx.x * 64;
    int w = threadIdx.x >> 6, lane = threadIdx.x & 63;
    int c = lane & 15, qd = lane >> 4;
    int mw = m0 + w * 16;
    const __bf16* B = Bt + g * (128 * 256);

    f32x4 acc[8] = {};
#pragma unroll
    for (int kc = 0; kc < 8; kc++) {
        bf16x8 a = *(const bf16x8*)(h + (mw + c) * L + kc * 32 + qd * 8);
#pragma unroll
        for (int nt = 0; nt < 8; nt++) {
            bf16x8 b = *(const bf16x8*)(B + (nt * 16 + c) * L + kc * 32 + qd * 8);
            acc[nt] = MFMA16(a, b, acc[nt]);
        }
    }
    if (g == 2 || g == 5) {
        // stage v-tile (64 n-rows x 128 d-cols) in LDS, then write Vt[d][n]
#pragma unroll
        for (int nt = 0; nt < 8; nt++)
#pragma unroll
            for (int r = 0; r < 4; r++)
                lv[w * 16 + 4 * qd + r][nt * 16 + c] = (__bf16)acc[nt][r];
        __syncthreads();
        __bf16* vt = Vt + (g / 3) * (128 * Nrows);
        int t = threadIdx.x;
        int d = t >> 1, nb = (t & 1) * 32;
#pragma unroll
        for (int j = 0; j < 4; j++) {
            bf16x8 o;
#pragma unroll
            for (int e = 0; e < 8; e++) o[e] = lv[nb + j * 8 + e][d];
            *(bf16x8*)(vt + d * Nrows + m0 + nb + j * 8) = o;
        }
    } else {
        __bf16* dst = (g == 0) ? q0 : (g == 1) ? k0 : (g == 3) ? q1 : k1;
#pragma unroll
        for (int nt = 0; nt < 8; nt++)
#pragma unroll
            for (int r = 0; r < 4; r++)
                dst[(mw + 4 * qd + r) * D + nt * 16 + c] = (__bf16)acc[nt][r];
    }
}

// ============================================================
// Flash attention (no-max online softmax: logits bounded |s|<~13).
// Grid = 512 blocks (qtile*2+head) -> 2 blocks/CU; head==XCD parity so each
// XCD's L2 holds one head's K+Vt (4MB): proven ~18MB FETCH pattern.
// Block = 256 threads (4 waves); each wave: ALL 32 Q-rows x disjoint
// 32-wide key slice of a 128-key step. kb/vb fully prefetched at the top
// of each step (round-2 structure: loads in flight during QK MFMA phase).
// ~190 regs/wave (126 VGPR + 64 AGPR) <= 256 -> 2 waves/SIMD, no spills.
// Main loop is barrier-free (P round-trip is wave-private LDS).
// ============================================================
__launch_bounds__(256, 2)
__global__ void k_flash(const __bf16* __restrict__ q0, const __bf16* __restrict__ k0,
                        const __bf16* __restrict__ q1, const __bf16* __restrict__ k1,
                        const __bf16* __restrict__ Vt, __bf16* __restrict__ O) {
    int head = blockIdx.x & 1;
    int qtile = blockIdx.x >> 1;       // 0..255
    int m0 = qtile * 32;
    const __bf16* qm = head ? q1 : q0;
    const __bf16* km = head ? k1 : k0;
    const __bf16* vt = Vt + head * (128 * Nrows);
    __bf16* Og = O + head * (Nrows * D);

    int tid = threadIdx.x;
    int w = tid >> 6, lane = tid & 63;
    int c = lane & 15, qd = lane >> 4;

    // LDS: Pb[4][32*56] bf16 (14336 B) aliased with obuf[4][32][16] f32 (8192 B);
    // l_red[4][32] + l_inv[32] tail. Total ~15KB -> 2 blocks/CU fine.
    __shared__ char smem[4 * 32 * 56 * 2 + 4 * 32 * 4 + 32 * 4];
    __bf16* Pb = (__bf16*)smem;
    float (*obuf)[32][16] = (float (*)[32][16])smem;
    float (*l_red)[32] = (float (*)[32])(smem + 4 * 32 * 56 * 2);
    float* l_inv = (float*)(smem + 4 * 32 * 56 * 2 + 4 * 32 * 4);

    bf16x8 aq[2][4];
#pragma unroll
    for (int mt = 0; mt < 2; mt++)
#pragma unroll
        for (int kc = 0; kc < 4; kc++)
            aq[mt][kc] = *(const bf16x8*)(qm + (m0 + mt * 16 + c) * D + kc * 32 + qd * 8);

    f32x4 oacc[2][8] = {};
    float lp[2][4] = {};
    __bf16* Pw = Pb + w * (32 * 56);

    for (int n0 = 0; n0 < Nrows; n0 += 128) {
        int nb = n0 + w * 32;            // this wave's key slice
        // prefetch ALL K and V fragments for this step (in flight during QK)
        bf16x8 kb[2][4], vb[8];
#pragma unroll
        for (int nt = 0; nt < 2; nt++)
#pragma unroll
            for (int kc = 0; kc < 4; kc++)
                kb[nt][kc] = *(const bf16x8*)(km + (nb + nt * 16 + c) * D + kc * 32 + qd * 8);
#pragma unroll
        for (int dvt = 0; dvt < 8; dvt++)
            vb[dvt] = *(const bf16x8*)(vt + (dvt * 16 + c) * Nrows + nb + qd * 8);

        // S = Q K^T, P = exp(S) -> wave-private LDS (A-layout target)
#pragma unroll
        for (int nt = 0; nt < 2; nt++) {
            f32x4 s[2] = {};
#pragma unroll
            for (int kc = 0; kc < 4; kc++) {
                s[0] = MFMA16(aq[0][kc], kb[nt][kc], s[0]);
                s[1] = MFMA16(aq[1][kc], kb[nt][kc], s[1]);
            }
#pragma unroll
            for (int mt = 0; mt < 2; mt++)
#pragma unroll
                for (int r = 0; r < 4; r++) {
                    float e = __expf(s[mt][r]);
                    lp[mt][r] += e;
                    Pw[(mt * 16 + 4 * qd + r) * 56 + nt * 16 + c] = (__bf16)e;
                }
        }
        // P·V
        bf16x8 ap[2];
#pragma unroll
        for (int mt = 0; mt < 2; mt++)
            ap[mt] = *(const bf16x8*)(Pw + (mt * 16 + c) * 56 + qd * 8);
#pragma unroll
        for (int dvt = 0; dvt < 8; dvt++) {
            oacc[0][dvt] = MFMA16(ap[0], vb[dvt], oacc[0][dvt]);
            oacc[1][dvt] = MFMA16(ap[1], vb[dvt], oacc[1][dvt]);
        }
    }

    // per-wave row sums of l
#pragma unroll
    for (int mt = 0; mt < 2; mt++)
#pragma unroll
        for (int r = 0; r < 4; r++) {
            float v = lp[mt][r];
            v += __shfl_xor(v, 1, 16);
            v += __shfl_xor(v, 2, 16);
            v += __shfl_xor(v, 4, 16);
            v += __shfl_xor(v, 8, 16);
            lp[mt][r] = v;
        }
    if (c == 0) {
#pragma unroll
        for (int mt = 0; mt < 2; mt++)
#pragma unroll
            for (int r = 0; r < 4; r++)
                l_red[w][mt * 16 + 4 * qd + r] = lp[mt][r];
    }
    __syncthreads();   // main loop + l_red done -> Pb->obuf alias safe
    if (tid < 32)
        l_inv[tid] = 1.0f / (l_red[0][tid] + l_red[1][tid] + l_red[2][tid] + l_red[3][tid]);

    // combine the 4 key-slice partials, one dv-tile at a time
    for (int dvt = 0; dvt < 8; dvt++) {
        __syncthreads();      // l_inv ready (iter 0); prior readers done (later iters)
#pragma unroll
        for (int mt = 0; mt < 2; mt++)
#pragma unroll
            for (int r = 0; r < 4; r++)
                obuf[w][mt * 16 + 4 * qd + r][c] = oacc[mt][dvt][r];
        __syncthreads();
        if (tid < 128) {
            int row = tid >> 2, col = (tid & 3) * 4;   // row 0..31
            f32x4 s = {0.f, 0.f, 0.f, 0.f};
#pragma unroll
            for (int ww = 0; ww < 4; ww++) s += *(const f32x4*)&obuf[ww][row][col];
            float il = l_inv[row];
            bf16x4 o;
#pragma unroll
            for (int e = 0; e < 4; e++) o[e] = (__bf16)(s[e] * il);
            *(bf16x4*)(Og + (m0 + row) * D + dvt * 16 + col) = o;
        }
    }
}

// ============================================================
// z = hf + O0 @ Vup0 + O1 @ Vup1   (fp32 residual + fp32 out)
// ============================================================
__launch_bounds__(256)
__global__ void k_gemm_vup(const __bf16* __restrict__ O, const __bf16* __restrict__ VupT,
                           const float* __restrict__ hf, float* __restrict__ z) {
    int n0 = blockIdx.y * 128;
    int m0 = blockIdx.x * 64;
    int w = threadIdx.x >> 6, lane = threadIdx.x & 63;
    int c = lane & 15, qd = lane >> 4;
    int mw = m0 + w * 16;

    f32x4 acc[8] = {};
#pragma unroll
    for (int kc = 0; kc < 8; kc++) {
        const __bf16* Oh = O + (kc >> 2) * (Nrows * D);
        const __bf16* Vh = VupT + (kc >> 2) * (L * D);
        int ko = (kc & 3) * 32 + qd * 8;
        bf16x8 a = *(const bf16x8*)(Oh + (mw + c) * D + ko);
#pragma unroll
        for (int nt = 0; nt < 8; nt++) {
            bf16x8 b = *(const bf16x8*)(Vh + (n0 + nt * 16 + c) * D + ko);
            acc[nt] = MFMA16(a, b, acc[nt]);
        }
    }
#pragma unroll
    for (int nt = 0; nt < 8; nt++)
#pragma unroll
        for (int r = 0; r < 4; r++) {
            int row = mw + 4 * qd + r;
            int col = n0 + nt * 16 + c;
            z[row * L + col] = acc[nt][r] + hf[row * L + col];
        }
}

// ============================================================
// out = relu(hin @ W^T + b); OutT = __bf16 (intermediate) or float (final)
// ============================================================
template <typename OutT>
__launch_bounds__(256)
__global__ void k_gemm_w(const __bf16* __restrict__ hin, const __bf16* __restrict__ W,
                         const float* __restrict__ bias, OutT* __restrict__ out) {
    int n0 = blockIdx.y * 128;
    int m0 = blockIdx.x * 64;
    int w = threadIdx.x >> 6, lane = threadIdx.x & 63;
    int c = lane & 15, qd = lane >> 4;
    int mw = m0 + w * 16;

    f32x4 acc[8] = {};
#pragma unroll
    for (int kc = 0; kc < 8; kc++) {
        bf16x8 a = *(const bf16x8*)(hin + (mw + c) * L + kc * 32 + qd * 8);
#pragma unroll
        for (int nt = 0; nt < 8; nt++) {
            bf16x8 b = *(const bf16x8*)(W + (n0 + nt * 16 + c) * L + kc * 32 + qd * 8);
            acc[nt] = MFMA16(a, b, acc[nt]);
        }
    }
#pragma unroll
    for (int nt = 0; nt < 8; nt++) {
        int col = n0 + nt * 16 + c;
        float bv = bias[col];
#pragma unroll
        for (int r = 0; r < 4; r++) {
            int row = mw + 4 * qd + r;
            float v = fmaxf(acc[nt][r] + bv, 0.0f);
            out[row * L + col] = (OutT)v;
        }
    }
}

// ============================================================
extern "C" void kernel_launch(void* const* d_in, const int* in_sizes, int n_in,
                              void* d_out, int out_size, void* d_ws, size_t ws_size,
                              hipStream_t stream) {
    (void)in_sizes; (void)n_in; (void)out_size; (void)ws_size;
    const float* x   = (const float*)d_in[0];
    const float* Q   = (const float*)d_in[1];
    const float* K   = (const float*)d_in[2];
    const float* Vd  = (const float*)d_in[3];
    const float* Vup = (const float*)d_in[4];
    const float* W   = (const float*)d_in[5];
    const float* b   = (const float*)d_in[6];
    float* out = (float*)d_out;

    char* ws = (char*)d_ws;
    size_t off = 0;
    auto alloc = [&](size_t bytes) -> void* {
        void* p = ws + off;
        off += (bytes + 255) & ~(size_t)255;
        return p;
    };
    float*  stats = (float*)alloc(4 * 256 * sizeof(float)); // sum1,sq1,sum2,sq2
    __bf16* Bt    = (__bf16*)alloc(6 * 128 * 256 * 2);
    __bf16* VupT  = (__bf16*)alloc(2 * 256 * 128 * 2);
    __bf16* Wb    = (__bf16*)alloc(2 * 256 * 256 * 2);
    __bf16* hb    = (__bf16*)alloc((size_t)Nrows * L * 2);
    float*  hf    = (float*)alloc((size_t)Nrows * L * 4);
    __bf16* q0    = (__bf16*)alloc((size_t)Nrows * D * 2);
    __bf16* k0    = (__bf16*)alloc((size_t)Nrows * D * 2);
    __bf16* q1    = (__bf16*)alloc((size_t)Nrows * D * 2);
    __bf16* k1    = (__bf16*)alloc((size_t)Nrows * D * 2);
    __bf16* Vt    = (__bf16*)alloc((size_t)2 * 128 * Nrows * 2);
    __bf16* O     = (__bf16*)alloc((size_t)2 * Nrows * D * 2);
    float*  z     = (float*)alloc((size_t)Nrows * L * 4);
    __bf16* h2    = (__bf16*)alloc((size_t)Nrows * L * 2);
    __bf16* h3    = (__bf16*)alloc((size_t)Nrows * L * 2);

    float* sum1 = stats, *sq1 = stats + 256, *sum2 = stats + 512, *sq2 = stats + 768;

    hipMemsetAsync(stats, 0, 4 * 256 * sizeof(float), stream);
    k_pre<<<1792, 256, 0, stream>>>(x, Q, K, Vd, Vup, W, Bt, VupT, Wb, sum1, sq1);
    k_bn_norm1<<<2048, 256, 0, stream>>>(x, sum1, sq1, hb, hf);
    k_gemm_qkv<<<dim3(128, 6), 256, 0, stream>>>(hb, Bt, q0, k0, q1, k1, Vt);
    k_flash<<<512, 256, 0, stream>>>(q0, k0, q1, k1, Vt, O);
    k_gemm_vup<<<dim3(128, 2), 256, 0, stream>>>(O, VupT, hf, z);
    k_bn_stats<<<256, 256, 0, stream>>>(z, sum2, sq2);
    k_bn_norm2<<<2048, 256, 0, stream>>>(z, sum2, sq2, h2);
    k_gemm_w<__bf16><<<dim3(128, 2), 256, 0, stream>>>(h2, Wb, b, h3);
    k_gemm_w<float><<<dim3(128, 2), 256, 0, stream>>>(h3, Wb + 256 * 256, b + 256, out);
}